// Round 6
// baseline (1905.234 us; speedup 1.0000x reference)
//
#include <hip/hip_runtime.h>
#include <hip/hip_fp16.h>
#include <stdint.h>
#include <stddef.h>

// LSTM B=512,T=128,D=256,H=256,C=128, gates (i,j,f,o), FORGET_BIAS=1.
// R6: recurrence split across 64 CUs (2 per batch-tile, halves exchange h
// through LLC each step with release/acquire flags). Rec is fully bf16 now
// (Wh register-resident: 32 frags = 128 VGPR). xproj unchanged from R5.

typedef __attribute__((ext_vector_type(8))) __bf16 bf16x8;
typedef __attribute__((ext_vector_type(4))) __bf16 bf16x4;
typedef __attribute__((ext_vector_type(4))) float  f32x4;

#define LDH   264          // bf16 row stride in xproj A-tile
#define ZPS   2097152ull   // Zx plane stride in uint2 (32*128*8*64)

__device__ __forceinline__ f32x4 mfma_bf16(bf16x8 a, bf16x8 b, f32x4 c) {
    return __builtin_amdgcn_mfma_f32_16x16x32_bf16(a, b, c, 0, 0, 0);
}
#define EXP2(x) __builtin_amdgcn_exp2f(x)
#define RCP(x)  __builtin_amdgcn_rcpf(x)
#define L2E  1.442695040f
#define L2E2 2.885390082f

// ---------------- 1) weight shuffle (both parts bf16 B-frags) ----------------
__global__ __launch_bounds__(256) void shuffle_w(const float* __restrict__ Wk,
                                                 __bf16* __restrict__ WF) {
    int id = blockIdx.x * 256 + threadIdx.x;
    int part = id >> 15;                              // 0 = Wx, 1 = Wh
    int i = id & 32767;
    int lane = i & 63, kt = (i >> 6) & 7, nt = i >> 9;
    int quad = lane >> 4, l16 = lane & 15;
    const float* src = Wk + (size_t)(part * 256 + kt * 32 + quad * 8) * 1024 + nt * 16 + l16;
    __bf16* dst = WF + (size_t)part * 262144 + ((size_t)(nt * 8 + kt) * 64 + lane) * 8;
#pragma unroll
    for (int j = 0; j < 8; ++j) dst[j] = (__bf16)src[(size_t)j * 1024];
}

// ---------------- 2) x-projection (plane-separated Zx) — as R5 ----------------
__global__ __launch_bounds__(512, 2) void xproj(const float* __restrict__ x,
        const __bf16* __restrict__ WxF, const float* __restrict__ bias,
        uint2* __restrict__ Zx) {
    __shared__ __attribute__((aligned(16))) __bf16 At[64 * LDH];
    const int tid = threadIdx.x, wv = tid >> 6, lane = tid & 63;
    const int l16 = lane & 15, quad = lane >> 4;
    const int rb = blockIdx.x & 31, tg = blockIdx.x >> 5;

#pragma unroll
    for (int rr = 0; rr < 8; ++rr) {
        int Arow = wv * 8 + rr;
        int tt = Arow >> 4, r = Arow & 15;
        const float4 xv = *((const float4*)(x + ((size_t)(rb * 16 + r) * 128 + tg * 4 + tt) * 256) + lane);
        bf16x4 xb = { (__bf16)xv.x, (__bf16)xv.y, (__bf16)xv.z, (__bf16)xv.w };
        *(bf16x4*)&At[Arow * LDH + lane * 4] = xb;
    }
    __syncthreads();

    f32x4 acc[4][8];
#pragma unroll
    for (int tt = 0; tt < 4; ++tt)
#pragma unroll
        for (int nt = 0; nt < 8; ++nt) acc[tt][nt] = (f32x4){0.f, 0.f, 0.f, 0.f};

#pragma unroll
    for (int kt = 0; kt < 8; ++kt) {
        bf16x8 af[4];
#pragma unroll
        for (int tt = 0; tt < 4; ++tt)
            af[tt] = *(const bf16x8*)&At[(tt * 16 + l16) * LDH + kt * 32 + quad * 8];
#pragma unroll
        for (int nt = 0; nt < 8; ++nt) {
            bf16x8 wf = *(const bf16x8*)&WxF[(((size_t)(wv * 8 + nt) * 8 + kt) * 64 + lane) * 8];
#pragma unroll
            for (int tt = 0; tt < 4; ++tt) acc[tt][nt] = mfma_bf16(af[tt], wf, acc[tt][nt]);
        }
    }

#pragma unroll
    for (int nt = 0; nt < 8; ++nt) {
        int col = wv * 128 + nt * 16 + l16;
        float bb = bias[col] + ((col >= 512 && col < 768) ? 1.0f : 0.0f);
#pragma unroll
        for (int tt = 0; tt < 4; ++tt) {
            int t = tg * 4 + tt;
            union { __half h[4]; uint2 u; } pk;
#pragma unroll
            for (int r = 0; r < 4; ++r) pk.h[r] = __float2half(acc[tt][nt][r] + bb);
            Zx[(size_t)wv * ZPS + ((size_t)(rb * 128 + t) * 8 + nt) * 64 + lane] = pk.u;
        }
    }
}

// ---------------- 3) recurrent loop: 64 blocks, 2 per batch-tile ----------------
__global__ __launch_bounds__(512, 2) void lstm_rec(const __bf16* __restrict__ WhF,
        const uint2* __restrict__ Zx, __bf16* __restrict__ Hx,
        int* __restrict__ flags, const float* __restrict__ wout,
        const float* __restrict__ bout, float* __restrict__ out) {
    // HtF: OWN-half h in A-frag order: [buf][k4(4)][lane(64)][8 bf16] = 4 KB/buf
    __shared__ __attribute__((aligned(16))) char HtF[2][4096];
    const int tid = threadIdx.x, wv = tid >> 6, lane = tid & 63;
    const int l16 = lane & 15, quad = lane >> 4;
    const int bid = blockIdx.x, rb = bid & 31, s = bid >> 5, pbid = bid ^ 32;

    // Wh bf16 B-frags for MY 512 z-cols: 32 x 16B = 128 VGPR (or AGPR)
    bf16x8 wreg[32];
#pragma unroll
    for (int g = 0; g < 4; ++g) {
        int ng = g * 16 + s * 8 + wv;           // col = g*256 + s*128 + wv*16 + l16
#pragma unroll
        for (int k = 0; k < 8; ++k)
            wreg[g * 8 + k] = *(const bf16x8*)&WhF[((size_t)(ng * 8 + k) * 64 + lane) * 8];
    }
    if (tid < 256) ((uint4*)HtF[0])[tid] = (uint4){0u, 0u, 0u, 0u};

    // scatter positions for my h (col = s*128 + wv*16 + l16, row = quad*4+r)
    const int quad_d = (2 * wv + (l16 >> 3)) & 3;
    const int lbase  = (wv >> 1) * 1024 + quad_d * 256 + quad * 64 + (l16 & 7) * 2; // bytes, +r*16
    const int gbase  = (wv >> 1) * 512 + quad_d * 128 + quad * 32 + (l16 & 7);      // bf16 idx, +r*8

    float c_[4] = {0.f, 0.f, 0.f, 0.f};
    float hr[4] = {0.f, 0.f, 0.f, 0.f};
    const size_t zi0 = ((size_t)rb * 128 * 8 + wv) * 64 + lane;
    uint2 zc[4], zn[4];
#pragma unroll
    for (int g = 0; g < 4; ++g) zc[g] = Zx[(size_t)(2 * g + s) * ZPS + zi0];
    bf16x8 zero8 = {(__bf16)0.f,(__bf16)0.f,(__bf16)0.f,(__bf16)0.f,
                    (__bf16)0.f,(__bf16)0.f,(__bf16)0.f,(__bf16)0.f};
    __syncthreads();

#pragma unroll 1
    for (int t = 0; t < 128; ++t) {
        if (t < 127) {                       // prefetch z(t+1), 4 coalesced 8B loads
            size_t zi = zi0 + (size_t)(t + 1) * 512;
#pragma unroll
            for (int g = 0; g < 4; ++g) zn[g] = Zx[(size_t)(2 * g + s) * ZPS + zi];
        }
        bf16x8 afo[4];                       // own-half A-frags (kt = 4s..4s+3)
#pragma unroll
        for (int k = 0; k < 4; ++k)
            afo[k] = *(const bf16x8*)&HtF[t & 1][k * 1024 + lane * 16];
        bf16x8 afp[4];                       // partner-half A-frags
        if (t > 0) {
            while (__hip_atomic_load(&flags[pbid], __ATOMIC_ACQUIRE,
                                     __HIP_MEMORY_SCOPE_AGENT) < t)
                __builtin_amdgcn_s_sleep(1);
            const __bf16* pb = Hx + ((size_t)(pbid * 2 + (t & 1))) * 2048;
#pragma unroll
            for (int k = 0; k < 4; ++k)
                afp[k] = *(const bf16x8*)&pb[(size_t)(k * 64 + lane) * 8];
        } else {
#pragma unroll
            for (int k = 0; k < 4; ++k) afp[k] = zero8;
        }

        f32x4 acc[4];
#pragma unroll
        for (int g = 0; g < 4; ++g) acc[g] = (f32x4){0.f, 0.f, 0.f, 0.f};
#pragma unroll
        for (int k = 0; k < 4; ++k)          // own kts first (LDS, ready)
#pragma unroll
            for (int g = 0; g < 4; ++g)
                acc[g] = mfma_bf16(afo[k], wreg[g * 8 + 4 * s + k], acc[g]);
#pragma unroll
        for (int k = 0; k < 4; ++k)          // partner kts (loads had time to land)
#pragma unroll
            for (int g = 0; g < 4; ++g)
                acc[g] = mfma_bf16(afp[k], wreg[g * 8 + 4 * (1 - s) + k], acc[g]);

        __bf16* myb = Hx + ((size_t)(bid * 2 + ((t + 1) & 1))) * 2048;
        char* ldsw = &HtF[(t + 1) & 1][0];
#pragma unroll
        for (int r = 0; r < 4; ++r) {
            float iv = acc[0][r] + __half2float(((const __half*)&zc[0])[r]);
            float jv = acc[1][r] + __half2float(((const __half*)&zc[1])[r]);
            float fv = acc[2][r] + __half2float(((const __half*)&zc[2])[r]);
            float ov = acc[3][r] + __half2float(((const __half*)&zc[3])[r]);
            float si = RCP(1.f + EXP2(-L2E * iv));      // rcp(inf)=0: clamp-free
            float sf = RCP(1.f + EXP2(-L2E * fv));
            float so = RCP(1.f + EXP2(-L2E * ov));
            float ej = EXP2(-L2E2 * fabsf(jv));         // exponent <= 0: no overflow
            float tj = copysignf((1.f - ej) * RCP(1.f + ej), jv);
            float c = c_[r] * sf + si * tj;
            c_[r] = c;
            float ec = EXP2(-L2E2 * fabsf(c));
            float tc = copysignf((1.f - ec) * RCP(1.f + ec), c);
            float h = tc * so;
            hr[r] = h;
            __bf16 hb = (__bf16)h;
            *(__bf16*)(ldsw + lbase + r * 16) = hb;     // own half -> LDS (A-frag)
            myb[gbase + r * 8] = hb;                    // own half -> LLC (A-frag)
        }
#pragma unroll
        for (int g = 0; g < 4; ++g) zc[g] = zn[g];
        __syncthreads();   // all LDS+global h stores drained (vmcnt0 at barrier)
        if (tid == 0)
            __hip_atomic_store(&flags[bid], t + 1, __ATOMIC_RELEASE,
                               __HIP_MEMORY_SCOPE_AGENT);
    }

    // ---- output projection: half s computes out-cols s*64..s*64+63 ----
    if (wv < 4) {
        while (__hip_atomic_load(&flags[pbid], __ATOMIC_ACQUIRE,
                                 __HIP_MEMORY_SCOPE_AGENT) < 128)
            __builtin_amdgcn_s_sleep(1);
        bf16x8 afo2[4], afp2[4];
        const __bf16* pb0 = Hx + (size_t)(pbid * 2 + 0) * 2048;   // h(128) in buf 0
#pragma unroll
        for (int k = 0; k < 4; ++k) {
            afo2[k] = *(const bf16x8*)&HtF[0][k * 1024 + lane * 16];
            afp2[k] = *(const bf16x8*)&pb0[(size_t)(k * 64 + lane) * 8];
        }
        int colo = s * 64 + wv * 16 + l16;
        f32x4 oa = {0.f, 0.f, 0.f, 0.f};
#pragma unroll
        for (int k = 0; k < 8; ++k) {
            bf16x8 wo;
#pragma unroll
            for (int j = 0; j < 8; ++j)
                wo[j] = (__bf16)wout[(size_t)(k * 32 + quad * 8 + j) * 128 + colo];
            bf16x8 a = ((k >> 2) == s) ? afo2[k & 3] : afp2[k & 3];
            oa = mfma_bf16(a, wo, oa);
        }
        float bo = bout[colo];
#pragma unroll
        for (int r = 0; r < 4; ++r)
            out[(size_t)(rb * 16 + quad * 4 + r) * 128 + colo] = oa[r] + bo;
    }
}

extern "C" void kernel_launch(void* const* d_in, const int* in_sizes, int n_in,
                              void* d_out, int out_size, void* d_ws, size_t ws_size,
                              hipStream_t stream) {
    const float* x    = (const float*)d_in[0];
    const float* Wk   = (const float*)d_in[1];
    const float* bias = (const float*)d_in[2];
    const float* wout = (const float*)d_in[3];
    const float* bout = (const float*)d_in[4];
    float* out = (float*)d_out;

    __bf16* WF    = (__bf16*)d_ws;                       // Wx frags [0,262144), Wh [262144,524288)
    __bf16* Hx    = (__bf16*)((char*)d_ws + 1048576);    // 64 blk x 2 buf x 2048 bf16 = 512 KB
    int*    flags = (int*)((char*)d_ws + 1572864);       // 64 ints (poison -> negative)
    uint2*  Zx    = (uint2*)((char*)d_ws + 2097152);     // 128 MB, 8 planes

    shuffle_w<<<256, 256, 0, stream>>>(Wk, WF);
    xproj<<<1024, 512, 0, stream>>>(x, WF, bias, Zx);
    lstm_rec<<<64, 512, 0, stream>>>(WF + 262144, Zx, Hx, flags, wout, bout, out);
}

// Round 7
// 937.478 us; speedup vs baseline: 2.0323x; 2.0323x over previous
//
#include <hip/hip_runtime.h>
#include <hip/hip_fp16.h>
#include <stdint.h>
#include <stddef.h>

// LSTM B=512,T=128,D=256,H=256,C=128, gates (i,j,f,o), FORGET_BIAS=1.
// R7: recurrence spread over 128 CUs with ZERO cross-block sync: each block
// owns 4 batch rows (MFMA m-dim 3/4-padded — idle CUs make padding free).
// Batch row b sits at MFMA row m=4b -> every lane holds exactly 2 valid h
// (acc[p][0]), cutting per-CU epilogue VALU 4x vs R5. 1 wave/SIMD, 512-VGPR
// budget -> Wh bf16 fully register-resident (64 frags = 256 VGPR), pure bf16.

typedef __attribute__((ext_vector_type(8))) __bf16 bf16x8;
typedef __attribute__((ext_vector_type(4))) __bf16 bf16x4;
typedef __attribute__((ext_vector_type(4))) float  f32x4;

#define LDH   264          // bf16 row stride in xproj A-tile
#define ZPS   2097152ull   // Zx plane stride in uint2 (32*128*8*64)

__device__ __forceinline__ f32x4 mfma_bf16(bf16x8 a, bf16x8 b, f32x4 c) {
    return __builtin_amdgcn_mfma_f32_16x16x32_bf16(a, b, c, 0, 0, 0);
}
#define EXP2(x) __builtin_amdgcn_exp2f(x)
#define RCP(x)  __builtin_amdgcn_rcpf(x)
#define L2E  1.442695040f
#define L2E2 2.885390082f

// ---------------- 1) weight shuffle (both parts bf16 B-frags) ----------------
__global__ __launch_bounds__(256) void shuffle_w(const float* __restrict__ Wk,
                                                 __bf16* __restrict__ WF) {
    int id = blockIdx.x * 256 + threadIdx.x;
    int part = id >> 15;                              // 0 = Wx, 1 = Wh
    int i = id & 32767;
    int lane = i & 63, kt = (i >> 6) & 7, nt = i >> 9;
    int quad = lane >> 4, l16 = lane & 15;
    const float* src = Wk + (size_t)(part * 256 + kt * 32 + quad * 8) * 1024 + nt * 16 + l16;
    __bf16* dst = WF + (size_t)part * 262144 + ((size_t)(nt * 8 + kt) * 64 + lane) * 8;
#pragma unroll
    for (int j = 0; j < 8; ++j) dst[j] = (__bf16)src[(size_t)j * 1024];
}

// ---------------- 2) x-projection (plane-separated Zx) — as R5 ----------------
__global__ __launch_bounds__(512, 2) void xproj(const float* __restrict__ x,
        const __bf16* __restrict__ WxF, const float* __restrict__ bias,
        uint2* __restrict__ Zx) {
    __shared__ __attribute__((aligned(16))) __bf16 At[64 * LDH];
    const int tid = threadIdx.x, wv = tid >> 6, lane = tid & 63;
    const int l16 = lane & 15, quad = lane >> 4;
    const int rb = blockIdx.x & 31, tg = blockIdx.x >> 5;

#pragma unroll
    for (int rr = 0; rr < 8; ++rr) {
        int Arow = wv * 8 + rr;
        int tt = Arow >> 4, r = Arow & 15;
        const float4 xv = *((const float4*)(x + ((size_t)(rb * 16 + r) * 128 + tg * 4 + tt) * 256) + lane);
        bf16x4 xb = { (__bf16)xv.x, (__bf16)xv.y, (__bf16)xv.z, (__bf16)xv.w };
        *(bf16x4*)&At[Arow * LDH + lane * 4] = xb;
    }
    __syncthreads();

    f32x4 acc[4][8];
#pragma unroll
    for (int tt = 0; tt < 4; ++tt)
#pragma unroll
        for (int nt = 0; nt < 8; ++nt) acc[tt][nt] = (f32x4){0.f, 0.f, 0.f, 0.f};

#pragma unroll
    for (int kt = 0; kt < 8; ++kt) {
        bf16x8 af[4];
#pragma unroll
        for (int tt = 0; tt < 4; ++tt)
            af[tt] = *(const bf16x8*)&At[(tt * 16 + l16) * LDH + kt * 32 + quad * 8];
#pragma unroll
        for (int nt = 0; nt < 8; ++nt) {
            bf16x8 wf = *(const bf16x8*)&WxF[(((size_t)(wv * 8 + nt) * 8 + kt) * 64 + lane) * 8];
#pragma unroll
            for (int tt = 0; tt < 4; ++tt) acc[tt][nt] = mfma_bf16(af[tt], wf, acc[tt][nt]);
        }
    }

#pragma unroll
    for (int nt = 0; nt < 8; ++nt) {
        int col = wv * 128 + nt * 16 + l16;
        float bb = bias[col] + ((col >= 512 && col < 768) ? 1.0f : 0.0f);
#pragma unroll
        for (int tt = 0; tt < 4; ++tt) {
            int t = tg * 4 + tt;
            union { __half h[4]; uint2 u; } pk;
#pragma unroll
            for (int r = 0; r < 4; ++r) pk.h[r] = __float2half(acc[tt][nt][r] + bb);
            Zx[(size_t)wv * ZPS + ((size_t)(rb * 128 + t) * 8 + nt) * 64 + lane] = pk.u;
        }
    }
}

// ---------------- 3) recurrent loop: 128 blocks x 4 batch rows ----------------
__global__ __launch_bounds__(512, 1) void lstm_rec(const __bf16* __restrict__ WhF,
        const uint2* __restrict__ Zx, const float* __restrict__ wout,
        const float* __restrict__ bout, float* __restrict__ out) {
    // Ht A-frag layout: [buf][kt(8)][lane(64)][8 bf16] = 8 KB/buf.
    // Only rows m=4b (b=0..3) ever written; rest stay zero.
    __shared__ __attribute__((aligned(16))) char HtF[2][8192];
    const int tid = threadIdx.x, wv = tid >> 6, lane = tid & 63;
    const int l16 = lane & 15, quad = lane >> 4;
    const int rbblk = blockIdx.x;            // 0..127: batch rows 4*rbblk..+3
    const int rb = rbblk >> 2, qb = rbblk & 3;

    // Wh bf16 B-frags, fully register-resident: 64 x 16B = 256 VGPR.
    // acc plane p = g*2+hf -> n-tile ng = (p>>1)*16 + (p&1)*8 + wv.
    bf16x8 wreg[64];
#pragma unroll
    for (int p = 0; p < 8; ++p) {
        int ng = (p >> 1) * 16 + (p & 1) * 8 + wv;
#pragma unroll
        for (int kt = 0; kt < 8; ++kt)
            wreg[kt * 8 + p] = *(const bf16x8*)&WhF[((size_t)(ng * 8 + kt) * 64 + lane) * 8];
    }
    // zero-init both Ht buffers (16 KB / 512 thr = 32 B each)
#pragma unroll
    for (int i = 0; i < 2; ++i)
        ((uint4*)HtF[0])[tid * 2 + i] = (uint4){0u, 0u, 0u, 0u};

    // h scatter address (A-frag position of h(b=quad, col)):
    // col(hf)=hf*128+wv*16+l16; kt=col>>5, quad_d=(col&31)>>3, j=col&7, m=4*quad
    const int col0 = wv * 16 + l16;
    const int sb0 = (((col0 >> 5) * 64 + (((col0 & 31) >> 3) * 16) + 4 * quad) * 16) + (col0 & 7) * 2;
    // hf=1: col+128 -> kt+4 -> +4096 bytes

    float c_[2] = {0.f, 0.f};
    const size_t zi0 = ((size_t)rb * 128 * 8 + wv) * 64 + qb * 16 + l16;
    uint2 zc[8], zn[8];
#pragma unroll
    for (int p = 0; p < 8; ++p) zc[p] = Zx[p * ZPS + zi0];
    __syncthreads();

#pragma unroll 1
    for (int t = 0; t < 128; ++t) {
        if (t < 127) {                       // prefetch z(t+1): 8 broadcast 8B loads
            size_t zi = zi0 + (size_t)(t + 1) * 512;
#pragma unroll
            for (int p = 0; p < 8; ++p) zn[p] = Zx[p * ZPS + zi];
        }

        f32x4 a0 = {0,0,0,0}, a1 = {0,0,0,0}, a2 = {0,0,0,0}, a3 = {0,0,0,0};
        f32x4 a4 = {0,0,0,0}, a5 = {0,0,0,0}, a6 = {0,0,0,0}, a7 = {0,0,0,0};
#pragma unroll
        for (int kt = 0; kt < 8; ++kt) {
            bf16x8 af = *(const bf16x8*)&HtF[t & 1][(kt * 64 + lane) * 16];
            a0 = mfma_bf16(af, wreg[kt * 8 + 0], a0);
            a1 = mfma_bf16(af, wreg[kt * 8 + 1], a1);
            a2 = mfma_bf16(af, wreg[kt * 8 + 2], a2);
            a3 = mfma_bf16(af, wreg[kt * 8 + 3], a3);
            a4 = mfma_bf16(af, wreg[kt * 8 + 4], a4);
            a5 = mfma_bf16(af, wreg[kt * 8 + 5], a5);
            a6 = mfma_bf16(af, wreg[kt * 8 + 6], a6);
            a7 = mfma_bf16(af, wreg[kt * 8 + 7], a7);
        }

        // z extract: plane p's uint2 holds rows qb*4+{0..3} as 4 fp16; mine = #quad
        float zz[8];
#pragma unroll
        for (int p = 0; p < 8; ++p) {
            unsigned w = (quad & 2) ? zc[p].y : zc[p].x;
            w = (quad & 1) ? (w >> 16) : (w & 0xffff);
            union { unsigned short u; __half h; } cv; cv.u = (unsigned short)w;
            zz[p] = __half2float(cv.h);
        }

        // epilogue: 2 h per lane (hf=0,1); valid acc element is [0] (m=4*quad)
        char* ldsw = &HtF[(t + 1) & 1][0];
        const float accv[8] = {a0[0], a1[0], a2[0], a3[0], a4[0], a5[0], a6[0], a7[0]};
#pragma unroll
        for (int hf = 0; hf < 2; ++hf) {
            float iv = accv[0 + hf] + zz[0 + hf];
            float jv = accv[2 + hf] + zz[2 + hf];
            float fv = accv[4 + hf] + zz[4 + hf];
            float ov = accv[6 + hf] + zz[6 + hf];
            float si = RCP(1.f + EXP2(-L2E * iv));      // rcp(inf)=0: clamp-free
            float sf = RCP(1.f + EXP2(-L2E * fv));
            float so = RCP(1.f + EXP2(-L2E * ov));
            float ej = EXP2(-L2E2 * fabsf(jv));
            float tj = copysignf((1.f - ej) * RCP(1.f + ej), jv);
            float c = c_[hf] * sf + si * tj;
            c_[hf] = c;
            float ec = EXP2(-L2E2 * fabsf(c));
            float tc = copysignf((1.f - ec) * RCP(1.f + ec), c);
            *(__bf16*)(ldsw + sb0 + hf * 4096) = (__bf16)(tc * so);
        }
#pragma unroll
        for (int p = 0; p < 8; ++p) zc[p] = zn[p];
        __syncthreads();   // publish Ht(t+1)
    }

    // ---- output projection: out[4,128] = h_last @ wout + bout ----
    // h_last A-frags in HtF[0]; wave wv -> out cols wv*16..+15; valid r=0 (m=4*quad)
    bf16x8 wo[8];
#pragma unroll
    for (int kt = 0; kt < 8; ++kt) {
        bf16x8 f;
#pragma unroll
        for (int j = 0; j < 8; ++j)
            f[j] = (__bf16)wout[(size_t)(kt * 32 + quad * 8 + j) * 128 + wv * 16 + l16];
        wo[kt] = f;
    }
    f32x4 oa = {0.f, 0.f, 0.f, 0.f};
#pragma unroll
    for (int kt = 0; kt < 8; ++kt) {
        bf16x8 af = *(const bf16x8*)&HtF[0][(kt * 64 + lane) * 16];
        oa = mfma_bf16(af, wo[kt], oa);
    }
    int colo = wv * 16 + l16;
    out[(size_t)(rbblk * 4 + quad) * 128 + colo] = oa[0] + bout[colo];
}

extern "C" void kernel_launch(void* const* d_in, const int* in_sizes, int n_in,
                              void* d_out, int out_size, void* d_ws, size_t ws_size,
                              hipStream_t stream) {
    const float* x    = (const float*)d_in[0];
    const float* Wk   = (const float*)d_in[1];
    const float* bias = (const float*)d_in[2];
    const float* wout = (const float*)d_in[3];
    const float* bout = (const float*)d_in[4];
    float* out = (float*)d_out;

    __bf16* WF = (__bf16*)d_ws;                      // Wx frags [0,262144), Wh [262144,524288)
    uint2*  Zx = (uint2*)((char*)d_ws + 2097152);    // 128 MB, 8 planes

    shuffle_w<<<256, 256, 0, stream>>>(Wk, WF);
    xproj<<<1024, 512, 0, stream>>>(x, WF, bias, Zx);
    lstm_rec<<<128, 512, 0, stream>>>(WF + 262144, Zx, wout, bout, out);
}

// Round 8
// 444.715 us; speedup vs baseline: 4.2842x; 2.1080x over previous
//
#include <hip/hip_runtime.h>
#include <hip/hip_fp16.h>
#include <stdint.h>
#include <stddef.h>

// LSTM B=512,T=128,D=256,H=256,C=128, gates (i,j,f,o), FORGET_BIAS=1.
// R8 = R7 structure (128 blocks x 4 batch rows, 2 h/lane epilogue, no cross-
// block sync) + R5 register recipe (fp8 Wh as long[64] -> 128 AGPRs, no spill;
// 512-thr block = 2 waves/SIMD caps budget at 256 regs — bf16 weights CANNOT fit).

typedef __attribute__((ext_vector_type(8))) __bf16 bf16x8;
typedef __attribute__((ext_vector_type(4))) __bf16 bf16x4;
typedef __attribute__((ext_vector_type(4))) float  f32x4;

#define LDH   264          // bf16 row stride (xproj A-tile, out staging)
#define ZPS   2097152ull   // Zx plane stride in uint2 (32*128*8*64)

__device__ __forceinline__ f32x4 mfma_bf16(bf16x8 a, bf16x8 b, f32x4 c) {
    return __builtin_amdgcn_mfma_f32_16x16x32_bf16(a, b, c, 0, 0, 0);
}
__device__ __forceinline__ f32x4 mfma_fp8(long a, long b, f32x4 c) {
    return __builtin_amdgcn_mfma_f32_16x16x32_fp8_fp8(a, b, c, 0, 0, 0);
}
#define EXP2(x) __builtin_amdgcn_exp2f(x)
#define RCP(x)  __builtin_amdgcn_rcpf(x)
#define L2E  1.442695040f
#define L2E2 2.885390082f
// sigmoid(x) = rcp(1+exp2(-L2E x));  tanh(x) = 2*rcp(1+exp2(-L2E2 x)) - 1
// (exp2->inf gives rcp->0: correct saturation, no clamps needed)

// ---------------- 1) weight shuffle: Wx -> bf16 frags, Wh -> fp8 frags ----------------
__global__ __launch_bounds__(256) void shuffle_w(const float* __restrict__ Wk,
                                                 __bf16* __restrict__ WxF,
                                                 unsigned char* __restrict__ WhF) {
    int id = blockIdx.x * 256 + threadIdx.x;
    int part = id >> 15;                              // 0 = Wx (bf16), 1 = Wh (fp8)
    int i = id & 32767;
    int lane = i & 63, kt = (i >> 6) & 7, nt = i >> 9;
    int quad = lane >> 4, l16 = lane & 15;
    const float* src = Wk + (size_t)(part * 256 + kt * 32 + quad * 8) * 1024 + nt * 16 + l16;
    float w[8];
#pragma unroll
    for (int j = 0; j < 8; ++j) w[j] = src[(size_t)j * 1024];
    if (part == 0) {
        __bf16* dst = WxF + ((size_t)(nt * 8 + kt) * 64 + lane) * 8;
#pragma unroll
        for (int j = 0; j < 8; ++j) dst[j] = (__bf16)w[j];
    } else {
        int a = __builtin_amdgcn_cvt_pk_fp8_f32(w[0], w[1], 0, false);
        a     = __builtin_amdgcn_cvt_pk_fp8_f32(w[2], w[3], a, true);
        int b = __builtin_amdgcn_cvt_pk_fp8_f32(w[4], w[5], 0, false);
        b     = __builtin_amdgcn_cvt_pk_fp8_f32(w[6], w[7], b, true);
        int2 v = {a, b};
        *(int2*)(WhF + ((size_t)(nt * 8 + kt) * 64 + lane) * 8) = v;
    }
}

// ---------------- 2) x-projection (plane-separated Zx) — as R5 ----------------
__global__ __launch_bounds__(512, 2) void xproj(const float* __restrict__ x,
        const __bf16* __restrict__ WxF, const float* __restrict__ bias,
        uint2* __restrict__ Zx) {
    __shared__ __attribute__((aligned(16))) __bf16 At[64 * LDH];
    const int tid = threadIdx.x, wv = tid >> 6, lane = tid & 63;
    const int l16 = lane & 15, quad = lane >> 4;
    const int rb = blockIdx.x & 31, tg = blockIdx.x >> 5;

#pragma unroll
    for (int rr = 0; rr < 8; ++rr) {
        int Arow = wv * 8 + rr;
        int tt = Arow >> 4, r = Arow & 15;
        const float4 xv = *((const float4*)(x + ((size_t)(rb * 16 + r) * 128 + tg * 4 + tt) * 256) + lane);
        bf16x4 xb = { (__bf16)xv.x, (__bf16)xv.y, (__bf16)xv.z, (__bf16)xv.w };
        *(bf16x4*)&At[Arow * LDH + lane * 4] = xb;
    }
    __syncthreads();

    f32x4 acc[4][8];
#pragma unroll
    for (int tt = 0; tt < 4; ++tt)
#pragma unroll
        for (int nt = 0; nt < 8; ++nt) acc[tt][nt] = (f32x4){0.f, 0.f, 0.f, 0.f};

#pragma unroll
    for (int kt = 0; kt < 8; ++kt) {
        bf16x8 af[4];
#pragma unroll
        for (int tt = 0; tt < 4; ++tt)
            af[tt] = *(const bf16x8*)&At[(tt * 16 + l16) * LDH + kt * 32 + quad * 8];
#pragma unroll
        for (int nt = 0; nt < 8; ++nt) {
            bf16x8 wf = *(const bf16x8*)&WxF[(((size_t)(wv * 8 + nt) * 8 + kt) * 64 + lane) * 8];
#pragma unroll
            for (int tt = 0; tt < 4; ++tt) acc[tt][nt] = mfma_bf16(af[tt], wf, acc[tt][nt]);
        }
    }

#pragma unroll
    for (int nt = 0; nt < 8; ++nt) {
        int col = wv * 128 + nt * 16 + l16;
        float bb = bias[col] + ((col >= 512 && col < 768) ? 1.0f : 0.0f);
#pragma unroll
        for (int tt = 0; tt < 4; ++tt) {
            int t = tg * 4 + tt;
            union { __half h[4]; uint2 u; } pk;
#pragma unroll
            for (int r = 0; r < 4; ++r) pk.h[r] = __float2half(acc[tt][nt][r] + bb);
            Zx[(size_t)wv * ZPS + ((size_t)(rb * 128 + t) * 8 + nt) * 64 + lane] = pk.u;
        }
    }
}

// ---------------- 3) recurrent loop: 128 blocks x 4 batch rows ----------------
__global__ __launch_bounds__(512, 2) void lstm_rec(const long* __restrict__ WhF,
        const uint2* __restrict__ Zx, const float* __restrict__ wout,
        const float* __restrict__ bout, float* __restrict__ out) {
    // Ht fp8 A-frag layout: [buf][kt(8)][lane(64)][8 B] = 4 KB/buf.
    // Only rows m=4b (b=0..3) written; rest stay zero (padding).
    __shared__ __attribute__((aligned(16))) char HtF[2][4096];
    __shared__ __attribute__((aligned(16))) __bf16 HtB[16 * LDH];   // out staging
    const int tid = threadIdx.x, wv = tid >> 6, lane = tid & 63;
    const int l16 = lane & 15, quad = lane >> 4;
    const int rbblk = blockIdx.x;            // batch rows 4*rbblk .. +3
    const int rb = rbblk >> 2, qb = rbblk & 3;

    // Wh fp8 B-frags: long[64] = 128 regs -> AGPRs (proven no-spill recipe, R5)
    long wreg[64];
#pragma unroll
    for (int p = 0; p < 8; ++p) {            // p = g*2+hf -> cols g*256+hf*128+wv*16+l16
        int ng = (p >> 1) * 16 + (p & 1) * 8 + wv;
#pragma unroll
        for (int kt = 0; kt < 8; ++kt)
            wreg[kt * 8 + p] = WhF[(size_t)(ng * 8 + kt) * 64 + lane];
    }
    ((uint4*)HtF[0])[tid] = (uint4){0u, 0u, 0u, 0u};   // 8 KB = 512 x 16 B

    // h scatter (fp8 A-frag position of col, row m=4*quad):
    // kt=col>>5, quad_d=(col&31)>>3, lane_d=quad_d*16+4*quad, byte j=col&7
    const int col0 = wv * 16 + l16;
    const int sb0 = (col0 >> 5) * 512 + (((col0 & 31) >> 3) * 16 + 4 * quad) * 8 + (col0 & 7);
    // hf=1 -> col+128 -> kt+4 -> +2048 bytes

    float c_[2] = {0.f, 0.f};
    float hr[2] = {0.f, 0.f};
    const size_t zi0 = ((size_t)rb * 1024 + wv) * 64 + qb * 16 + l16;
    uint2 zc[8], zn[8];
#pragma unroll
    for (int p = 0; p < 8; ++p) zc[p] = Zx[p * ZPS + zi0];
    __syncthreads();

#pragma unroll 1
    for (int t = 0; t < 128; ++t) {
        if (t < 127) {                       // prefetch z(t+1); lands during MFMA
            size_t zi = zi0 + (size_t)(t + 1) * 512;
#pragma unroll
            for (int p = 0; p < 8; ++p) zn[p] = Zx[p * ZPS + zi];
        }

        long af[8];
#pragma unroll
        for (int kt = 0; kt < 8; ++kt)
            af[kt] = *(const long*)&HtF[t & 1][kt * 512 + lane * 8];

        f32x4 acc[8];
#pragma unroll
        for (int p = 0; p < 8; ++p) acc[p] = (f32x4){0.f, 0.f, 0.f, 0.f};
#pragma unroll
        for (int kt = 0; kt < 8; ++kt)
#pragma unroll
            for (int p = 0; p < 8; ++p)
                acc[p] = mfma_fp8(af[kt], wreg[kt * 8 + p], acc[p]);

        // z extract: plane p's uint2 holds 4 fp16 rows qb*4+{0..3}; mine = #quad
        float zz[8];
#pragma unroll
        for (int p = 0; p < 8; ++p) {
            unsigned w = (quad & 2) ? zc[p].y : zc[p].x;
            w = (quad & 1) ? (w >> 16) : (w & 0xffff);
            union { unsigned short u; __half h; } cv; cv.u = (unsigned short)w;
            zz[p] = __half2float(cv.h);
        }

        // epilogue: 2 h per lane; valid acc element = [0] (row m = 4*quad)
        char* ldsw = &HtF[(t + 1) & 1][0];
#pragma unroll
        for (int hf = 0; hf < 2; ++hf) {
            float iv = acc[0 + hf][0] + zz[0 + hf];
            float jv = acc[2 + hf][0] + zz[2 + hf];
            float fv = acc[4 + hf][0] + zz[4 + hf];
            float ov = acc[6 + hf][0] + zz[6 + hf];
            float si = RCP(1.f + EXP2(-L2E * iv));
            float sf = RCP(1.f + EXP2(-L2E * fv));
            float so = RCP(1.f + EXP2(-L2E * ov));
            float tj = 2.f * RCP(1.f + EXP2(-L2E2 * jv)) - 1.f;
            float c = c_[hf] * sf + si * tj;
            c_[hf] = c;
            float tc = 2.f * RCP(1.f + EXP2(-L2E2 * c)) - 1.f;
            float h = tc * so;
            hr[hf] = h;
            unsigned pb = (unsigned)__builtin_amdgcn_cvt_pk_fp8_f32(h, h, 0, false);
            ldsw[sb0 + hf * 2048] = (char)pb;
        }
#pragma unroll
        for (int p = 0; p < 8; ++p) zc[p] = zn[p];
        __syncthreads();   // publish Ht(t+1)
    }

    // ---- output projection: fp32 h -> bf16 staging tile -> MFMA ----
    for (int i = tid; i < 16 * LDH; i += 512) HtB[i] = (__bf16)0.f;
    __syncthreads();
#pragma unroll
    for (int hf = 0; hf < 2; ++hf)
        HtB[(4 * quad) * LDH + hf * 128 + col0] = (__bf16)hr[hf];
    __syncthreads();

    bf16x8 wo[8];
#pragma unroll
    for (int kt = 0; kt < 8; ++kt) {
        bf16x8 f;
#pragma unroll
        for (int j = 0; j < 8; ++j)
            f[j] = (__bf16)wout[(size_t)(kt * 32 + quad * 8 + j) * 128 + col0];
        wo[kt] = f;
    }
    f32x4 oa = {0.f, 0.f, 0.f, 0.f};
#pragma unroll
    for (int kt = 0; kt < 8; ++kt) {
        bf16x8 af = *(const bf16x8*)&HtB[l16 * LDH + kt * 32 + quad * 8];
        oa = mfma_bf16(af, wo[kt], oa);
    }
    out[(size_t)(rbblk * 4 + quad) * 128 + col0] = oa[0] + bout[col0];
}

extern "C" void kernel_launch(void* const* d_in, const int* in_sizes, int n_in,
                              void* d_out, int out_size, void* d_ws, size_t ws_size,
                              hipStream_t stream) {
    const float* x    = (const float*)d_in[0];
    const float* Wk   = (const float*)d_in[1];
    const float* bias = (const float*)d_in[2];
    const float* wout = (const float*)d_in[3];
    const float* bout = (const float*)d_in[4];
    float* out = (float*)d_out;

    __bf16*        WxF = (__bf16*)d_ws;                      // 512 KB
    unsigned char* WhF = (unsigned char*)d_ws + 524288;      // 256 KB (fp8)
    uint2*         Zx  = (uint2*)((char*)d_ws + 2097152);    // 128 MB, 8 planes

    shuffle_w<<<256, 256, 0, stream>>>(Wk, WxF, WhF);
    xproj<<<1024, 512, 0, stream>>>(x, WxF, bias, Zx);
    lstm_rec<<<128, 512, 0, stream>>>((const long*)WhF, Zx, wout, bout, out);
}

// Round 9
// 436.926 us; speedup vs baseline: 4.3605x; 1.0178x over previous
//
#include <hip/hip_runtime.h>
#include <hip/hip_fp16.h>
#include <stdint.h>
#include <stddef.h>

// LSTM B=512,T=128,D=256,H=256,C=128, gates (i,j,f,o), FORGET_BIAS=1.
// R9 = R8 + recurrent MFMA switched to MX-scaled fp8 K=128 (2x rate):
//   mfma_scale_f32_16x16x128_f8f6f4, unit scales (0x7F = 2^0). With uniform
//   scales any consistent A/B k-permutation is exact, so the simple
//   k = quad*32+j byte layout is safe. Wh = 16 x v8i32 = 128 regs (fits).
//   Ht = plain fp8 [16][272] rows (2-way LDS aliasing = free), 4 b128 reads.

typedef __attribute__((ext_vector_type(8))) __bf16 bf16x8;
typedef __attribute__((ext_vector_type(4))) __bf16 bf16x4;
typedef __attribute__((ext_vector_type(4))) float  f32x4;
typedef __attribute__((ext_vector_type(8))) int    i32x8;

#define LDH   264          // bf16 row stride (xproj A-tile, out staging)
#define LDF   272          // fp8 Ht row stride in bytes (256 + 16)
#define ZPS   2097152ull   // Zx plane stride in uint2 (32*128*8*64)
#define SONE  0x7F7F7F7F   // E8M0 unit scales (all blocks = 2^0)

__device__ __forceinline__ f32x4 mfma_bf16(bf16x8 a, bf16x8 b, f32x4 c) {
    return __builtin_amdgcn_mfma_f32_16x16x32_bf16(a, b, c, 0, 0, 0);
}
#define EXP2(x) __builtin_amdgcn_exp2f(x)
#define RCP(x)  __builtin_amdgcn_rcpf(x)
#define L2E  1.442695040f
#define L2E2 2.885390082f

// ---------------- 1) weight shuffle ----------------
// Wx -> bf16 16x16x32 B-frags (for xproj). Wh -> fp8 K=128 B-frags:
// frag (ng, kt128): lane holds B[k=kt128*128+quad*32+j][n=ng*16+l16], j=0..31.
__global__ __launch_bounds__(256) void shuffle_w(const float* __restrict__ Wk,
                                                 __bf16* __restrict__ WxF,
                                                 unsigned char* __restrict__ WhF) {
    int id = blockIdx.x * 256 + threadIdx.x;
    if (id < 32768) {                                  // Wx part (rows 0..255)
        int lane = id & 63, kt = (id >> 6) & 7, nt = id >> 9;
        int quad = lane >> 4, l16 = lane & 15;
        const float* src = Wk + (size_t)(kt * 32 + quad * 8) * 1024 + nt * 16 + l16;
        __bf16* dst = WxF + ((size_t)(nt * 8 + kt) * 64 + lane) * 8;
#pragma unroll
        for (int j = 0; j < 8; ++j) dst[j] = (__bf16)src[(size_t)j * 1024];
    } else if (id < 40960) {                           // Wh part (rows 256..511)
        int i = id - 32768;
        int lane = i & 63, kt = (i >> 6) & 1, ng = i >> 7;
        int n = ng * 16 + (lane & 15);
        int kb = 256 + kt * 128 + (lane >> 4) * 32;
        int* dst = (int*)(WhF + (((size_t)ng * 2 + kt) * 64 + lane) * 32);
#pragma unroll
        for (int d = 0; d < 8; ++d) {
            float w0 = Wk[(size_t)(kb + 4 * d + 0) * 1024 + n];
            float w1 = Wk[(size_t)(kb + 4 * d + 1) * 1024 + n];
            float w2 = Wk[(size_t)(kb + 4 * d + 2) * 1024 + n];
            float w3 = Wk[(size_t)(kb + 4 * d + 3) * 1024 + n];
            int lo = __builtin_amdgcn_cvt_pk_fp8_f32(w0, w1, 0, false);
            dst[d]  = __builtin_amdgcn_cvt_pk_fp8_f32(w2, w3, lo, true);
        }
    }
}

// ---------------- 2) x-projection (plane-separated Zx) — as R5/R8 ----------------
__global__ __launch_bounds__(512, 2) void xproj(const float* __restrict__ x,
        const __bf16* __restrict__ WxF, const float* __restrict__ bias,
        uint2* __restrict__ Zx) {
    __shared__ __attribute__((aligned(16))) __bf16 At[64 * LDH];
    const int tid = threadIdx.x, wv = tid >> 6, lane = tid & 63;
    const int l16 = lane & 15, quad = lane >> 4;
    const int rb = blockIdx.x & 31, tg = blockIdx.x >> 5;

#pragma unroll
    for (int rr = 0; rr < 8; ++rr) {
        int Arow = wv * 8 + rr;
        int tt = Arow >> 4, r = Arow & 15;
        const float4 xv = *((const float4*)(x + ((size_t)(rb * 16 + r) * 128 + tg * 4 + tt) * 256) + lane);
        bf16x4 xb = { (__bf16)xv.x, (__bf16)xv.y, (__bf16)xv.z, (__bf16)xv.w };
        *(bf16x4*)&At[Arow * LDH + lane * 4] = xb;
    }
    __syncthreads();

    f32x4 acc[4][8];
#pragma unroll
    for (int tt = 0; tt < 4; ++tt)
#pragma unroll
        for (int nt = 0; nt < 8; ++nt) acc[tt][nt] = (f32x4){0.f, 0.f, 0.f, 0.f};

#pragma unroll
    for (int kt = 0; kt < 8; ++kt) {
        bf16x8 af[4];
#pragma unroll
        for (int tt = 0; tt < 4; ++tt)
            af[tt] = *(const bf16x8*)&At[(tt * 16 + l16) * LDH + kt * 32 + quad * 8];
#pragma unroll
        for (int nt = 0; nt < 8; ++nt) {
            bf16x8 wf = *(const bf16x8*)&WxF[(((size_t)(wv * 8 + nt) * 8 + kt) * 64 + lane) * 8];
#pragma unroll
            for (int tt = 0; tt < 4; ++tt) acc[tt][nt] = mfma_bf16(af[tt], wf, acc[tt][nt]);
        }
    }

#pragma unroll
    for (int nt = 0; nt < 8; ++nt) {
        int col = wv * 128 + nt * 16 + l16;
        float bb = bias[col] + ((col >= 512 && col < 768) ? 1.0f : 0.0f);
#pragma unroll
        for (int tt = 0; tt < 4; ++tt) {
            int t = tg * 4 + tt;
            union { __half h[4]; uint2 u; } pk;
#pragma unroll
            for (int r = 0; r < 4; ++r) pk.h[r] = __float2half(acc[tt][nt][r] + bb);
            Zx[(size_t)wv * ZPS + ((size_t)(rb * 128 + t) * 8 + nt) * 64 + lane] = pk.u;
        }
    }
}

// ---------------- 3) recurrent loop: 128 blocks x 4 batch rows ----------------
__global__ __launch_bounds__(512, 2) void lstm_rec(const unsigned char* __restrict__ WhF,
        const uint2* __restrict__ Zx, const float* __restrict__ wout,
        const float* __restrict__ bout, float* __restrict__ out) {
    // Ht: plain fp8 matrix [16 rows][272 B], double-buffered. Rows m=4b hold
    // batch rows b=0..3; other rows stay zero (m-padding).
    __shared__ __attribute__((aligned(16))) unsigned char HtF[2][16 * LDF];
    __shared__ __attribute__((aligned(16))) __bf16 HtB[16 * LDH];   // out staging
    const int tid = threadIdx.x, wv = tid >> 6, lane = tid & 63;
    const int l16 = lane & 15, quad = lane >> 4;
    const int rbblk = blockIdx.x;            // batch rows 4*rbblk .. +3
    const int rb = rbblk >> 2, qb = rbblk & 3;

    // Wh MX B-frags: 16 x v8i32 = 128 regs (p = g*2+hf, kt128 = 0,1)
    i32x8 wreg[16];
#pragma unroll
    for (int p = 0; p < 8; ++p) {
        int ng = (p >> 1) * 16 + (p & 1) * 8 + wv;   // cols g*256+hf*128+wv*16+l16
#pragma unroll
        for (int kt = 0; kt < 2; ++kt) {
            const uint4* wp = (const uint4*)(WhF + (((size_t)ng * 2 + kt) * 64 + lane) * 32);
            uint4 lo = wp[0], hi = wp[1];
            wreg[p * 2 + kt] = (i32x8){(int)lo.x, (int)lo.y, (int)lo.z, (int)lo.w,
                                       (int)hi.x, (int)hi.y, (int)hi.z, (int)hi.w};
        }
    }
    for (int i = tid; i < (16 * LDF * 2) / 4; i += 512) ((uint*)HtF[0])[i] = 0u;

    const int col0 = wv * 16 + l16;
    float c_[2] = {0.f, 0.f};
    float hr[2] = {0.f, 0.f};
    const size_t zi0 = ((size_t)rb * 1024 + wv) * 64 + qb * 16 + l16;
    uint2 zc[8], zn[8];
#pragma unroll
    for (int p = 0; p < 8; ++p) zc[p] = Zx[p * ZPS + zi0];
    __syncthreads();

#pragma unroll 1
    for (int t = 0; t < 128; ++t) {
        if (t < 127) {                       // prefetch z(t+1); lands during MFMA
            size_t zi = zi0 + (size_t)(t + 1) * 512;
#pragma unroll
            for (int p = 0; p < 8; ++p) zn[p] = Zx[p * ZPS + zi];
        }

        // A-frags: lane reads h row m=l16, bytes k=kt*128+quad*32..+31
        i32x8 afr[2];
#pragma unroll
        for (int kt = 0; kt < 2; ++kt) {
            const uint4* ap = (const uint4*)&HtF[t & 1][l16 * LDF + kt * 128 + quad * 32];
            uint4 lo = ap[0], hi = ap[1];
            afr[kt] = (i32x8){(int)lo.x, (int)lo.y, (int)lo.z, (int)lo.w,
                              (int)hi.x, (int)hi.y, (int)hi.z, (int)hi.w};
        }

        f32x4 acc[8];
#pragma unroll
        for (int p = 0; p < 8; ++p) acc[p] = (f32x4){0.f, 0.f, 0.f, 0.f};
#pragma unroll
        for (int kt = 0; kt < 2; ++kt)
#pragma unroll
            for (int p = 0; p < 8; ++p)
                acc[p] = __builtin_amdgcn_mfma_scale_f32_16x16x128_f8f6f4(
                    afr[kt], wreg[p * 2 + kt], acc[p], 0, 0, 0, SONE, 0, SONE);

        // z extract: plane p's uint2 holds 4 fp16 rows qb*4+{0..3}; mine = #quad
        float zz[8];
#pragma unroll
        for (int p = 0; p < 8; ++p) {
            unsigned w = (quad & 2) ? zc[p].y : zc[p].x;
            w = (quad & 1) ? (w >> 16) : (w & 0xffff);
            union { unsigned short u; __half h; } cv; cv.u = (unsigned short)w;
            zz[p] = __half2float(cv.h);
        }

        // epilogue: 2 h per lane; valid acc element = [0] (row m = 4*quad)
        unsigned char* ldsw = &HtF[(t + 1) & 1][0];
#pragma unroll
        for (int hf = 0; hf < 2; ++hf) {
            float iv = acc[0 + hf][0] + zz[0 + hf];
            float jv = acc[2 + hf][0] + zz[2 + hf];
            float fv = acc[4 + hf][0] + zz[4 + hf];
            float ov = acc[6 + hf][0] + zz[6 + hf];
            float si = RCP(1.f + EXP2(-L2E * iv));
            float sf = RCP(1.f + EXP2(-L2E * fv));
            float so = RCP(1.f + EXP2(-L2E * ov));
            float tj = 2.f * RCP(1.f + EXP2(-L2E2 * jv)) - 1.f;
            float c = c_[hf] * sf + si * tj;
            c_[hf] = c;
            float tc = 2.f * RCP(1.f + EXP2(-L2E2 * c)) - 1.f;
            float h = tc * so;
            hr[hf] = h;
            unsigned pb = (unsigned)__builtin_amdgcn_cvt_pk_fp8_f32(h, h, 0, false);
            ldsw[(4 * quad) * LDF + hf * 128 + col0] = (unsigned char)pb;
        }
#pragma unroll
        for (int p = 0; p < 8; ++p) zc[p] = zn[p];
        __syncthreads();   // publish Ht(t+1)
    }

    // ---- output projection: fp32 h -> bf16 staging tile -> MFMA ----
    for (int i = tid; i < 16 * LDH; i += 512) HtB[i] = (__bf16)0.f;
    __syncthreads();
#pragma unroll
    for (int hf = 0; hf < 2; ++hf)
        HtB[(4 * quad) * LDH + hf * 128 + col0] = (__bf16)hr[hf];
    __syncthreads();

    bf16x8 wo[8];
#pragma unroll
    for (int kt = 0; kt < 8; ++kt) {
        bf16x8 f;
#pragma unroll
        for (int j = 0; j < 8; ++j)
            f[j] = (__bf16)wout[(size_t)(kt * 32 + quad * 8 + j) * 128 + col0];
        wo[kt] = f;
    }
    f32x4 oa = {0.f, 0.f, 0.f, 0.f};
#pragma unroll
    for (int kt = 0; kt < 8; ++kt) {
        bf16x8 af = *(const bf16x8*)&HtB[l16 * LDH + kt * 32 + quad * 8];
        oa = mfma_bf16(af, wo[kt], oa);
    }
    out[(size_t)(rbblk * 4 + quad) * 128 + col0] = oa[0] + bout[col0];
}

extern "C" void kernel_launch(void* const* d_in, const int* in_sizes, int n_in,
                              void* d_out, int out_size, void* d_ws, size_t ws_size,
                              hipStream_t stream) {
    const float* x    = (const float*)d_in[0];
    const float* Wk   = (const float*)d_in[1];
    const float* bias = (const float*)d_in[2];
    const float* wout = (const float*)d_in[3];
    const float* bout = (const float*)d_in[4];
    float* out = (float*)d_out;

    __bf16*        WxF = (__bf16*)d_ws;                      // 512 KB
    unsigned char* WhF = (unsigned char*)d_ws + 524288;      // 256 KB (fp8 MX frags)
    uint2*         Zx  = (uint2*)((char*)d_ws + 2097152);    // 128 MB, 8 planes

    shuffle_w<<<160, 256, 0, stream>>>(Wk, WxF, WhF);
    xproj<<<1024, 512, 0, stream>>>(x, WxF, bias, Zx);
    lstm_rec<<<128, 512, 0, stream>>>(WhF, Zx, wout, bout, out);
}